// Round 1
// baseline (20433.109 us; speedup 1.0000x reference)
//
#include <hip/hip_runtime.h>
#include <math.h>

#define Bq 512
#define Tq 64
#define Hq 450
#define Lq 56
#define Vq 780
#define Mq 8
#define TBq (Tq*Bq)        // 32768
#define Sq (TBq+2)         // 32770
#define KPq (Hq+Lq)        // 506
#define KSq (Lq+2*Hq)      // 956
#define NROWS (TBq+Bq)     // 33280
#define CHUNK 4160
#define NCHUNK 8

#define BMT 64
#define BNT 64
#define BKT 16

__device__ __forceinline__ float sigmf(float x){ return 1.0f/(1.0f+expf(-x)); }

// ---------------- generic NT GEMM tile body ----------------
// C[i,j] = sum_k A(i,k) * Bw[j*ldb + k]; A supplied via lambda (gather-fused).
template<class AL>
__device__ __forceinline__ void gemm_body(AL&& aload,
    const float* __restrict__ Bw, int ldb,
    int Mr, int Nr, int Kr, int row0, int col0, float acc[4][4])
{
    __shared__ __align__(16) float As[BKT][BMT];
    __shared__ __align__(16) float Bs[BKT][BNT];
    const int tid = threadIdx.x;
    const int tx = tid & 15, ty = tid >> 4;
    const int lr = tid >> 2;          // 0..63
    const int lk = (tid & 3) * 4;     // 0,4,8,12
#pragma unroll
    for (int i=0;i<4;i++)
#pragma unroll
        for (int j=0;j<4;j++) acc[i][j]=0.f;

    for (int k0 = 0; k0 < Kr; k0 += BKT) {
        const int arow = row0 + lr;
        const bool rok = arow < Mr;
#pragma unroll
        for (int q=0;q<4;q++){
            int kk = k0 + lk + q;
            As[lk+q][lr] = (rok && kk < Kr) ? aload(arow, kk) : 0.f;
        }
        const int bcol = col0 + lr;
        const bool cok = bcol < Nr;
        const float* bp = Bw + (size_t)bcol * ldb;
#pragma unroll
        for (int q=0;q<4;q++){
            int kk = k0 + lk + q;
            Bs[lk+q][lr] = (cok && kk < Kr) ? bp[kk] : 0.f;
        }
        __syncthreads();
#pragma unroll
        for (int k=0;k<BKT;k++){
            const float4 av = *(const float4*)&As[k][ty*4];
            const float4 bv = *(const float4*)&Bs[k][tx*4];
            const float a[4] = {av.x,av.y,av.z,av.w};
            const float b[4] = {bv.x,bv.y,bv.z,bv.w};
#pragma unroll
            for (int i=0;i<4;i++)
#pragma unroll
                for (int j=0;j<4;j++)
                    acc[i][j] = fmaf(a[i], b[j], acc[i][j]);
        }
        __syncthreads();
    }
}

// ---------------- scan kernels ----------------
__global__ void scan_prep(int t, const int* __restrict__ x_wid,
                          const int* __restrict__ h_nei_idx,
                          const float* __restrict__ emb,
                          const float* __restrict__ h_buf,
                          float* __restrict__ xz, float* __restrict__ xh,
                          float* __restrict__ hnei, float* __restrict__ sum_h)
{
    int b = blockIdx.x;
    int wid = x_wid[t*Bq + b];
    int idx[Mq];
#pragma unroll
    for (int m=0;m<Mq;m++) idx[m] = h_nei_idx[(size_t)(t*Bq+b)*Mq + m];
    for (int j = threadIdx.x; j < Hq; j += blockDim.x) {
        float x = emb[(size_t)wid*Hq + j];
        xz[(size_t)b*(2*Hq)+j] = x;
        xh[(size_t)b*(2*Hq)+j] = x;
        float s = 0.f;
#pragma unroll
        for (int m=0;m<Mq;m++){
            float v = h_buf[(size_t)idx[m]*Hq + j];
            hnei[(size_t)(b*Mq+m)*Hq + j] = v;
            s += v;
        }
        xz[(size_t)b*(2*Hq)+Hq+j] = s;
        sum_h[(size_t)b*Hq+j] = s;
    }
}

// three GRU GEMMs in one launch, selected by blockIdx.z
__global__ __launch_bounds__(256) void gemm3_gru(
    const float* __restrict__ xz, const float* __restrict__ hnei,
    const float* __restrict__ Wz, const float* __restrict__ Wr, const float* __restrict__ Ur,
    float* __restrict__ pre_z, float* __restrict__ pre_r, float* __restrict__ urb)
{
    int z = blockIdx.z;
    const float* A; const float* Bw; float* C; int lda, Kr, Mr;
    if (z==0){ A=xz;   lda=2*Hq; Bw=Wz; Kr=2*Hq; Mr=Bq;     C=pre_z; }
    else if (z==1){ A=xz; lda=2*Hq; Bw=Wr; Kr=Hq; Mr=Bq;    C=pre_r; }
    else { A=hnei; lda=Hq; Bw=Ur; Kr=Hq; Mr=Bq*Mq;          C=urb; }
    int row0 = blockIdx.y*BMT, col0 = blockIdx.x*BNT;
    if (row0 >= Mr) return;
    float acc[4][4];
    gemm_body([&](int r,int k){ return A[(size_t)r*lda+k]; }, Bw, Kr, Mr, Hq, Kr, row0, col0, acc);
    int tx = threadIdx.x & 15, ty = threadIdx.x >> 4;
#pragma unroll
    for (int i=0;i<4;i++){ int row=row0+ty*4+i; if(row>=Mr) continue;
#pragma unroll
      for (int j=0;j<4;j++){ int col=col0+tx*4+j; if(col>=Hq) continue;
        C[(size_t)row*Hq+col]=acc[i][j]; } }
}

__global__ void gated_k(const float* __restrict__ pre_r, const float* __restrict__ br,
                        const float* __restrict__ urb, const float* __restrict__ hnei,
                        float* __restrict__ xh)
{
    int b = blockIdx.x;
    for (int j = threadIdx.x; j < Hq; j += blockDim.x){
        float pr = pre_r[(size_t)b*Hq+j] + br[j];
        float g = 0.f;
#pragma unroll
        for (int m=0;m<Mq;m++){
            float u  = urb [(size_t)(b*Mq+m)*Hq + j];
            float hv = hnei[(size_t)(b*Mq+m)*Hq + j];
            g += sigmf(pr + u) * hv;
        }
        xh[(size_t)b*(2*Hq) + Hq + j] = g;
    }
}

__global__ __launch_bounds__(256) void gemm_gru4(int t,
    const float* __restrict__ xh, const float* __restrict__ Wh,
    const float* __restrict__ pre_z, const float* __restrict__ sum_h,
    const float* __restrict__ bz, const float* __restrict__ bh,
    const int* __restrict__ valid, float* __restrict__ h_buf)
{
    int row0 = blockIdx.y*BMT, col0 = blockIdx.x*BNT;
    float acc[4][4];
    gemm_body([&](int r,int k){ return xh[(size_t)r*(2*Hq)+k]; }, Wh, 2*Hq, Bq, Hq, 2*Hq, row0, col0, acc);
    int tx = threadIdx.x & 15, ty = threadIdx.x >> 4;
#pragma unroll
    for (int i=0;i<4;i++){
        int b = row0 + ty*4 + i; if (b >= Bq) continue;
        int vld = valid[t*Bq + b];
#pragma unroll
        for (int j=0;j<4;j++){
            int col = col0 + tx*4 + j; if (col >= Hq) continue;
            float ht = tanhf(acc[i][j] + bh[col]);
            float zz = sigmf(pre_z[(size_t)b*Hq+col] + bz[col]);
            float nh = (1.f - zz) * sum_h[(size_t)b*Hq+col] + zz * ht;
            if (vld) h_buf[(size_t)(1 + t*Bq + b)*Hq + col] = nh;
        }
    }
}

// ---------------- pred phase ----------------
__global__ __launch_bounds__(256) void gemm_pred(int cs,
    const float* __restrict__ h_buf, const float* __restrict__ tree_vecs,
    const float* __restrict__ Wm, const float* __restrict__ bW, float* __restrict__ pv)
{
    int row0 = blockIdx.y*BMT, col0 = blockIdx.x*BNT;
    float acc[4][4];
    auto aload = [&](int r,int k)->float{
        int gr = cs + r;
        if (k < Hq) return (gr < Bq) ? 0.f : h_buf[(size_t)(1 + gr - Bq)*Hq + k];
        int b = (gr < Bq) ? gr : ((gr - Bq) & (Bq-1));
        return tree_vecs[(size_t)b*Lq + (k - Hq)];
    };
    gemm_body(aload, Wm, KPq, CHUNK, Hq, KPq, row0, col0, acc);
    int tx = threadIdx.x & 15, ty = threadIdx.x >> 4;
#pragma unroll
    for (int i=0;i<4;i++){ int row=row0+ty*4+i; if(row>=CHUNK) continue;
#pragma unroll
      for (int j=0;j<4;j++){ int col=col0+tx*4+j; if(col>=Hq) continue;
        pv[(size_t)row*Hq+col] = fmaxf(acc[i][j] + bW[col], 0.f); } }
}

__global__ __launch_bounds__(256) void gemm_nt(
    const float* __restrict__ A, int lda,
    const float* __restrict__ Bw, int ldb,
    const float* __restrict__ bias,
    float* __restrict__ C, int ldc,
    int Mr, int Nr, int Kr)
{
    int row0 = blockIdx.y*BMT, col0 = blockIdx.x*BNT;
    if (row0 >= Mr) return;
    float acc[4][4];
    gemm_body([&](int r,int k){ return A[(size_t)r*lda+k]; }, Bw, ldb, Mr, Nr, Kr, row0, col0, acc);
    int tx = threadIdx.x & 15, ty = threadIdx.x >> 4;
#pragma unroll
    for (int i=0;i<4;i++){ int row=row0+ty*4+i; if(row>=Mr) continue;
#pragma unroll
      for (int j=0;j<4;j++){ int col=col0+tx*4+j; if(col>=Nr) continue;
        C[(size_t)row*ldc+col] = acc[i][j] + bias[col]; } }
}

__global__ __launch_bounds__(256) void pred_reduce(int cs,
    const float* __restrict__ scores, const int* __restrict__ pred_wid,
    const int* __restrict__ root_wid, const int* __restrict__ valid,
    const int* __restrict__ direction, float* __restrict__ accv)
{
    __shared__ float rv[256]; __shared__ int ri[256]; __shared__ float rs[256];
    int r = blockIdx.x;
    int gr = cs + r;
    float mask; int tgt;
    if (gr < Bq){ mask = 1.f; tgt = root_wid[gr]; }
    else { int s = gr - Bq; mask = (float)(valid[s]*direction[s]); tgt = pred_wid[s]; }
    const float* sc = scores + (size_t)r*Vq;
    int tid = threadIdx.x;
    float bv = -INFINITY; int bi = 0;
    for (int j=tid;j<Vq;j+=256){ float v = sc[j]; if (v > bv){ bv=v; bi=j; } }
    rv[tid]=bv; ri[tid]=bi; __syncthreads();
    for (int off=128; off; off>>=1){
        if (tid < off){
            float v2 = rv[tid+off]; int i2 = ri[tid+off];
            if (v2 > rv[tid] || (v2 == rv[tid] && i2 < ri[tid])){ rv[tid]=v2; ri[tid]=i2; }
        }
        __syncthreads();
    }
    float gmax = rv[0]; int gidx = ri[0];
    float ls = 0.f;
    for (int j=tid;j<Vq;j+=256) ls += expf(sc[j]-gmax);
    rs[tid]=ls; __syncthreads();
    for (int off=128; off; off>>=1){ if (tid<off) rs[tid]+=rs[tid+off]; __syncthreads(); }
    if (tid==0){
        float lse = gmax + logf(rs[0]);
        float ce = lse - sc[tgt];
        atomicAdd(&accv[0], ce*mask);
        atomicAdd(&accv[1], (gidx==tgt ? 1.f : 0.f)*mask);
        atomicAdd(&accv[2], mask);
    }
}

// ---------------- stop phase ----------------
__global__ void curo_k(int cs, const int* __restrict__ o_nei_idx,
                       const int* __restrict__ root_o_nei_idx,
                       const float* __restrict__ h_buf, float* __restrict__ curo)
{
    int r = blockIdx.x;
    int gr = cs + r;
    int idx[Mq];
    if (gr < TBq){
        int t = gr >> 9;   // gr / B
#pragma unroll
        for (int m=0;m<Mq;m++){
            int ix = o_nei_idx[(size_t)gr*Mq + m];
            idx[m] = (ix <= t*Bq) ? ix : 0;   // h_buf row 0 is always zero
        }
    } else {
#pragma unroll
        for (int m=0;m<Mq;m++) idx[m] = root_o_nei_idx[(size_t)(gr-TBq)*Mq + m];
    }
    for (int j=threadIdx.x;j<Hq;j+=blockDim.x){
        float s = 0.f;
#pragma unroll
        for (int m=0;m<Mq;m++) s += h_buf[(size_t)idx[m]*Hq + j];
        curo[(size_t)r*Hq + j] = s;
    }
}

__global__ __launch_bounds__(256) void gemm_stop(int cs,
    const int* __restrict__ x_wid, const int* __restrict__ root_wid,
    const float* __restrict__ emb, const float* __restrict__ curo,
    const float* __restrict__ tree_vecs,
    const float* __restrict__ U, const float* __restrict__ bU, float* __restrict__ sv)
{
    int row0 = blockIdx.y*BMT, col0 = blockIdx.x*BNT;
    float acc[4][4];
    auto aload = [&](int r,int k)->float{
        int gr = cs + r;
        if (k < Hq){
            int wid = (gr < TBq) ? x_wid[gr] : root_wid[gr - TBq];
            return emb[(size_t)wid*Hq + k];
        }
        if (k < 2*Hq) return curo[(size_t)r*Hq + (k - Hq)];
        int b = (gr < TBq) ? (gr & (Bq-1)) : (gr - TBq);
        return tree_vecs[(size_t)b*Lq + (k - 2*Hq)];
    };
    gemm_body(aload, U, KSq, CHUNK, Hq, KSq, row0, col0, acc);
    int tx = threadIdx.x & 15, ty = threadIdx.x >> 4;
#pragma unroll
    for (int i=0;i<4;i++){ int row=row0+ty*4+i; if(row>=CHUNK) continue;
#pragma unroll
      for (int j=0;j<4;j++){ int col=col0+tx*4+j; if(col>=Hq) continue;
        sv[(size_t)row*Hq+col] = fmaxf(acc[i][j] + bU[col], 0.f); } }
}

__global__ void stop_reduce(int cs, const float* __restrict__ sv,
    const float* __restrict__ Us, const float* __restrict__ bUs,
    const int* __restrict__ valid, const int* __restrict__ direction,
    float* __restrict__ accv)
{
    int r = blockIdx.x; int gr = cs + r;
    int lane = threadIdx.x;
    const float* row = sv + (size_t)r*Hq;
    float p = 0.f;
    for (int j=lane;j<Hq;j+=64) p += row[j]*Us[j];
    for (int off=32; off; off>>=1) p += __shfl_xor(p, off);
    if (lane==0){
        float ss = p + bUs[0];
        float stgt, sm;
        if (gr < TBq){ stgt = (float)direction[gr]; sm = (float)valid[gr]; }
        else { stgt = 0.f; sm = 1.f; }
        float bce = fmaxf(ss, 0.f) - ss*stgt + log1pf(expf(-fabsf(ss)));
        float stop = (ss >= 0.f) ? 1.f : 0.f;
        atomicAdd(&accv[3], bce*sm);
        atomicAdd(&accv[4], ((stop==stgt)?1.f:0.f)*sm);
        atomicAdd(&accv[5], sm);
    }
}

__global__ void finalize_k(const float* __restrict__ accv, float* __restrict__ out){
    if (threadIdx.x==0 && blockIdx.x==0){
        out[0] = accv[0] / (float)Bq;
        out[1] = accv[3] / (float)Bq;
        out[2] = accv[1] / accv[2];
        out[3] = accv[4] / accv[5];
    }
}

extern "C" void kernel_launch(void* const* d_in, const int* in_sizes, int n_in,
                              void* d_out, int out_size, void* d_ws, size_t ws_size,
                              hipStream_t stream) {
    (void)in_sizes; (void)n_in; (void)out_size; (void)ws_size;
    const float* tree_vecs = (const float*)d_in[0];
    const int*   x_wid     = (const int*)d_in[1];
    const int*   pred_wid  = (const int*)d_in[2];
    const int*   root_wid  = (const int*)d_in[3];
    const int*   h_nei_idx = (const int*)d_in[4];
    const int*   o_nei_idx = (const int*)d_in[5];
    const int*   root_o_nei= (const int*)d_in[6];
    const int*   valid     = (const int*)d_in[7];
    const int*   direction = (const int*)d_in[8];
    const float* emb       = (const float*)d_in[9];
    const float* Wz        = (const float*)d_in[10];
    const float* bz        = (const float*)d_in[11];
    const float* Wr        = (const float*)d_in[12];
    const float* br        = (const float*)d_in[13];
    const float* Ur        = (const float*)d_in[14];
    const float* Wh        = (const float*)d_in[15];
    const float* bh        = (const float*)d_in[16];
    const float* Wm        = (const float*)d_in[17];
    const float* bW        = (const float*)d_in[18];
    const float* U         = (const float*)d_in[19];
    const float* bU        = (const float*)d_in[20];
    const float* Wo        = (const float*)d_in[21];
    const float* bWo       = (const float*)d_in[22];
    const float* Us        = (const float*)d_in[23];
    const float* bUs       = (const float*)d_in[24];

    float* ws    = (float*)d_ws;
    float* h_buf = ws;
    float* hnei  = h_buf + (size_t)Sq*Hq;
    float* xz    = hnei  + (size_t)Bq*Mq*Hq;
    float* xh    = xz    + (size_t)Bq*2*Hq;
    float* pre_z = xh    + (size_t)Bq*2*Hq;
    float* pre_r = pre_z + (size_t)Bq*Hq;
    float* urb   = pre_r + (size_t)Bq*Hq;
    float* sum_h = urb   + (size_t)Bq*Mq*Hq;
    float* accv  = sum_h + (size_t)Bq*Hq;
    float* pv    = accv  + 16;                    // reused as curo in stop phase
    float* scb   = pv    + (size_t)CHUNK*Hq;      // reused as sv in stop phase

    hipMemsetAsync(h_buf, 0, sizeof(float)*(size_t)Sq*Hq, stream);
    hipMemsetAsync(accv, 0, sizeof(float)*16, stream);

    for (int t=0;t<Tq;t++){
        scan_prep<<<Bq, 256, 0, stream>>>(t, x_wid, h_nei_idx, emb, h_buf, xz, xh, hnei, sum_h);
        gemm3_gru<<<dim3(8, 64, 3), 256, 0, stream>>>(xz, hnei, Wz, Wr, Ur, pre_z, pre_r, urb);
        gated_k<<<Bq, 256, 0, stream>>>(pre_r, br, urb, hnei, xh);
        gemm_gru4<<<dim3(8, 8), 256, 0, stream>>>(t, xh, Wh, pre_z, sum_h, bz, bh, valid, h_buf);
    }
    for (int c=0;c<NCHUNK;c++){
        int cs = c*CHUNK;
        gemm_pred<<<dim3(8, CHUNK/BMT), 256, 0, stream>>>(cs, h_buf, tree_vecs, Wm, bW, pv);
        gemm_nt<<<dim3((Vq+BNT-1)/BNT, CHUNK/BMT), 256, 0, stream>>>(pv, Hq, Wo, Hq, bWo, scb, Vq, CHUNK, Vq, Hq);
        pred_reduce<<<CHUNK, 256, 0, stream>>>(cs, scb, pred_wid, root_wid, valid, direction, accv);
    }
    for (int c=0;c<NCHUNK;c++){
        int cs = c*CHUNK;
        curo_k<<<CHUNK, 256, 0, stream>>>(cs, o_nei_idx, root_o_nei, h_buf, pv);
        gemm_stop<<<dim3(8, CHUNK/BMT), 256, 0, stream>>>(cs, x_wid, root_wid, emb, pv, tree_vecs, U, bU, scb);
        stop_reduce<<<CHUNK, 64, 0, stream>>>(cs, scb, Us, bUs, valid, direction, accv);
    }
    finalize_k<<<1, 64, 0, stream>>>(accv, (float*)d_out);
}

// Round 2
// 5622.834 us; speedup vs baseline: 3.6340x; 3.6340x over previous
//
#include <hip/hip_runtime.h>
#include <math.h>

#define Bq 512
#define Tq 64
#define Hq 450
#define Lq 56
#define Vq 780
#define Mq 8
#define TBq 32768
#define Sq 32770
#define HP 480          // padded H (bf16 row stride, mult of 32)
#define F32S 464        // f32 row stride for H-sized rows
#define KZ 960          // Kpad for Wz/Wh (two 480 segments)
#define KR 480
#define KP1 544         // pred GEMM1 Kpad (480 + 64)
#define KS 1024         // stop Kpad (480+480+64)
#define CH 3328         // pred score chunk rows (26*128)
#define NCH 10

using bf16x8 = __attribute__((ext_vector_type(8))) __bf16;
using f32x4  = __attribute__((ext_vector_type(4))) float;

__device__ __forceinline__ ushort f2bf(float f){
    union { float f; unsigned u; } c; c.f = f;
    unsigned u = c.u;
    unsigned r = (u + 0x7FFFu + ((u >> 16) & 1u)) >> 16;
    return (ushort)r;
}
__device__ __forceinline__ float bf2f(ushort h){
    union { unsigned u; float f; } c; c.u = ((unsigned)h) << 16;
    return c.f;
}
__device__ __forceinline__ float sigmf(float x){ return 1.f/(1.f+expf(-x)); }

// ---------- weight/embedding converter: f32 [Nsrc][Ksrc] -> bf16 [Npad][Kpad]
// dst segment s starts at dst col s*480, takes src cols [sum(l<s), +ls)
__global__ void convW_k(const float* __restrict__ src, ushort* __restrict__ dst,
                        int Nsrc, int Ksrc, int Kpad, int l0, int l1, int l2)
{
    int n = blockIdx.x;
    for (int k = threadIdx.x; k < Kpad; k += blockDim.x){
        float v = 0.f;
        if (n < Nsrc){
            int seg = k / 480; int off = k - seg*480;
            int slen = seg==0 ? l0 : (seg==1 ? l1 : l2);
            int soff = seg==0 ? 0  : (seg==1 ? l0 : l0+l1);
            if (off < slen) v = src[(size_t)n*Ksrc + soff + off];
        }
        dst[(size_t)n*Kpad + k] = f2bf(v);
    }
}

// ---------- MFMA GEMM body: C(128x64) tile, A gathered via aptr, B=[Npad][ldb] bf16
// aptr(which,k0): pointer to element k0 of this thread's A row (which=0 -> row tid>>2, 1 -> +64)
template<class APtr>
__device__ __forceinline__ void mgemm(APtr&& aptr, const ushort* __restrict__ Bw, int ldb,
                                      int KT, int col0, f32x4 acc[4][2])
{
    __shared__ __align__(16) char As[128*80];
    __shared__ __align__(16) char Bs[64*80];
    const int tid = threadIdx.x;
    const int lane = tid & 63;
    const int w = tid >> 6, wm = w >> 1, wn = w & 1;
    const int ac = (tid & 3) * 8;                       // k elem offset of this thread's 16B chunk
    const size_t boff = (size_t)(col0 + (tid >> 2)) * ldb;

    uint4 ra0, ra1, rb;
    auto ld = [&](int k0){
        ra0 = *(const uint4*)(aptr(0, k0) + ac);
        ra1 = *(const uint4*)(aptr(1, k0) + ac);
        rb  = *(const uint4*)(Bw + boff + k0 + ac);
    };
    ld(0);
#pragma unroll
    for (int f=0; f<4; f++)
#pragma unroll
        for (int g=0; g<2; g++) acc[f][g] = (f32x4){0.f,0.f,0.f,0.f};

    char* awr0 = As + (tid>>2)*80 + (tid&3)*16;
    char* awr1 = As + ((tid>>2)+64)*80 + (tid&3)*16;
    char* bwr  = Bs + (tid>>2)*80 + (tid&3)*16;
    const char* ard = As + (wm*64 + (lane&15))*80 + (lane>>4)*16;
    const char* brd = Bs + (wn*32 + (lane&15))*80 + (lane>>4)*16;

    for (int kt=0; kt<KT; ++kt){
        __syncthreads();
        *(uint4*)awr0 = ra0;
        *(uint4*)awr1 = ra1;
        *(uint4*)bwr  = rb;
        __syncthreads();
        if (kt+1 < KT) ld((kt+1)*32);
        bf16x8 bF[2];
#pragma unroll
        for (int g=0; g<2; g++) bF[g] = *(const bf16x8*)(brd + g*16*80);
#pragma unroll
        for (int f=0; f<4; f++){
            bf16x8 aF = *(const bf16x8*)(ard + f*16*80);
#pragma unroll
            for (int g=0; g<2; g++)
                acc[f][g] = __builtin_amdgcn_mfma_f32_16x16x32_bf16(aF, bF[g], acc[f][g], 0, 0, 0);
        }
    }
}

// C/D mapping (m89-verified): col = lane&15, row = (lane>>4)*4 + j
#define EPI_PRE  const int lane = threadIdx.x & 63; const int w_ = threadIdx.x >> 6; \
                 const int wm = w_ >> 1, wn = w_ & 1;

// ---------- scan: sum_h (bf16) ----------
__global__ void prep_k(int t, const int* __restrict__ h_nei_idx,
                       const ushort* __restrict__ hbuf, ushort* __restrict__ sumh)
{
    int b = blockIdx.x;
    const int* ip = h_nei_idx + (size_t)(t*Bq + b)*Mq;
    int idx[Mq];
#pragma unroll
    for (int m=0;m<Mq;m++) idx[m] = ip[m];
    int j0 = threadIdx.x * 4;
    if (j0 >= HP) return;
    float s0=0,s1=0,s2=0,s3=0;
#pragma unroll
    for (int m=0;m<Mq;m++){
        uint2 v = *(const uint2*)(hbuf + (size_t)idx[m]*HP + j0);
        s0 += bf2f((ushort)(v.x & 0xffff)); s1 += bf2f((ushort)(v.x >> 16));
        s2 += bf2f((ushort)(v.y & 0xffff)); s3 += bf2f((ushort)(v.y >> 16));
    }
    uint2 o;
    o.x = (unsigned)f2bf(s0) | ((unsigned)f2bf(s1) << 16);
    o.y = (unsigned)f2bf(s2) | ((unsigned)f2bf(s3) << 16);
    *(uint2*)(sumh + (size_t)b*HP + j0) = o;
}

// ---------- scan: z, r, u GEMMs fused by blockIdx.z ----------
__global__ __launch_bounds__(256) void zru_k(int t,
    const int* __restrict__ x_wid, const int* __restrict__ h_nei_idx,
    const ushort* __restrict__ embb, const ushort* __restrict__ sumh,
    const ushort* __restrict__ hbuf,
    const ushort* __restrict__ WzP, const ushort* __restrict__ WrP, const ushort* __restrict__ UrP,
    float* __restrict__ pre_z, float* __restrict__ pre_r, float* __restrict__ urb)
{
    const int z = blockIdx.z;
    if (z < 2 && blockIdx.y >= 4) return;
    const int row0 = blockIdx.y * 128, col0 = blockIdx.x * 64;
    const int tid = threadIdx.x;
    const int r0 = row0 + (tid >> 2), r1 = r0 + 64;

    const ushort *p00, *p01 = nullptr, *p10, *p11 = nullptr;
    const ushort* Bw; float* out; int KT, ldb;
    if (z == 2){
        p00 = hbuf + (size_t)h_nei_idx[t*4096 + r0] * HP;
        p10 = hbuf + (size_t)h_nei_idx[t*4096 + r1] * HP;
        Bw = UrP; out = urb; KT = 15; ldb = KR;
    } else {
        p00 = embb + (size_t)x_wid[t*Bq + r0] * HP;
        p10 = embb + (size_t)x_wid[t*Bq + r1] * HP;
        if (z == 0){ p01 = sumh + (size_t)r0*HP; p11 = sumh + (size_t)r1*HP;
                     Bw = WzP; out = pre_z; KT = 30; ldb = KZ; }
        else       { Bw = WrP; out = pre_r; KT = 15; ldb = KR; }
    }
    f32x4 acc[4][2];
    auto aptr = [&](int which, int k0)->const ushort*{
        if (k0 < 480) return (which ? p10 : p00) + k0;
        return (which ? p11 : p01) + (k0 - 480);
    };
    mgemm(aptr, Bw, ldb, KT, col0, acc);
    EPI_PRE
#pragma unroll
    for (int f=0; f<4; f++)
#pragma unroll
      for (int g=0; g<2; g++){
        int col = col0 + wn*32 + g*16 + (lane & 15);
        if (col >= Hq) continue;
#pragma unroll
        for (int j=0; j<4; j++){
            int row = row0 + wm*64 + f*16 + ((lane>>4)<<2) + j;
            out[(size_t)row*F32S + col] = acc[f][g][j];
        }
      }
}

// ---------- scan: gated sum (bf16 out) ----------
__global__ void gated_k(int t, const int* __restrict__ h_nei_idx,
                        const ushort* __restrict__ hbuf,
                        const float* __restrict__ pre_r, const float* __restrict__ br,
                        const float* __restrict__ urb, ushort* __restrict__ xh2)
{
    int b = blockIdx.x;
    const int* ip = h_nei_idx + (size_t)(t*Bq + b)*Mq;
    int idx[Mq];
#pragma unroll
    for (int m=0;m<Mq;m++) idx[m] = ip[m];
    int j0 = threadIdx.x * 4;
    if (j0 >= HP) return;
    ushort o[4];
#pragma unroll
    for (int e=0;e<4;e++){
        int j = j0 + e;
        float g = 0.f;
        if (j < Hq){
            float pr = pre_r[(size_t)b*F32S + j] + br[j];
#pragma unroll
            for (int m=0;m<Mq;m++){
                float u  = urb[(size_t)(b*Mq+m)*F32S + j];
                float hv = bf2f(hbuf[(size_t)idx[m]*HP + j]);
                g += sigmf(pr + u) * hv;
            }
        }
        o[e] = f2bf(g);
    }
    uint2 ov; ov.x = (unsigned)o[0] | ((unsigned)o[1]<<16);
    ov.y = (unsigned)o[2] | ((unsigned)o[3]<<16);
    *(uint2*)(xh2 + (size_t)b*HP + j0) = ov;
}

// ---------- scan: Wh GEMM + GRU blend epilogue ----------
__global__ __launch_bounds__(256) void wh_k(int t,
    const int* __restrict__ x_wid, const ushort* __restrict__ embb,
    const ushort* __restrict__ xh2, const ushort* __restrict__ WhP,
    const float* __restrict__ pre_z, const ushort* __restrict__ sumh,
    const float* __restrict__ bz, const float* __restrict__ bh,
    const int* __restrict__ valid, ushort* __restrict__ hbuf)
{
    const int row0 = blockIdx.y * 128, col0 = blockIdx.x * 64;
    const int tid = threadIdx.x;
    const int r0 = row0 + (tid>>2), r1 = r0 + 64;
    const ushort* p00 = embb + (size_t)x_wid[t*Bq + r0]*HP;
    const ushort* p10 = embb + (size_t)x_wid[t*Bq + r1]*HP;
    const ushort* p01 = xh2 + (size_t)r0*HP;
    const ushort* p11 = xh2 + (size_t)r1*HP;
    f32x4 acc[4][2];
    auto aptr = [&](int which,int k0)->const ushort*{
        if (k0 < 480) return (which ? p10 : p00) + k0;
        return (which ? p11 : p01) + (k0 - 480);
    };
    mgemm(aptr, WhP, KZ, 30, col0, acc);
    EPI_PRE
#pragma unroll
    for (int f=0; f<4; f++)
#pragma unroll
      for (int g=0; g<2; g++){
        int col = col0 + wn*32 + g*16 + (lane & 15);
        if (col >= Hq) continue;
        float bzc = bz[col], bhc = bh[col];
#pragma unroll
        for (int j=0; j<4; j++){
            int b = row0 + wm*64 + f*16 + ((lane>>4)<<2) + j;
            float zz = sigmf(pre_z[(size_t)b*F32S + col] + bzc);
            float ht = tanhf(acc[f][g][j] + bhc);
            float sh = bf2f(sumh[(size_t)b*HP + col]);
            float nh = (1.f - zz)*sh + zz*ht;
            if (valid[t*Bq + b])
                hbuf[(size_t)(1 + t*Bq + b)*HP + col] = f2bf(nh);
        }
      }
}

// ---------- pred GEMM1: [hidden|tv] @ W^T, relu, bf16 out ----------
__global__ __launch_bounds__(256) void pred1_k(
    const ushort* __restrict__ hbuf, const ushort* __restrict__ treeb,
    const ushort* __restrict__ WP_, const float* __restrict__ bW,
    ushort* __restrict__ pv)
{
    const int row0 = blockIdx.y*128, col0 = blockIdx.x*64;
    const int tid = threadIdx.x;
    int gr0 = row0 + (tid>>2), gr1 = gr0 + 64;
    const ushort* p00 = (gr0 < Bq) ? hbuf : hbuf + (size_t)(1 + gr0 - Bq)*HP;  // row0 of hbuf is all-zero
    const ushort* p10 = (gr1 < Bq) ? hbuf : hbuf + (size_t)(1 + gr1 - Bq)*HP;
    int b0 = (gr0 < Bq) ? gr0 : ((gr0 - Bq) & (Bq-1));
    int b1 = (gr1 < Bq) ? gr1 : ((gr1 - Bq) & (Bq-1));
    const ushort* p01 = treeb + (size_t)b0*64;
    const ushort* p11 = treeb + (size_t)b1*64;
    f32x4 acc[4][2];
    auto aptr = [&](int which,int k0)->const ushort*{
        if (k0 < 480) return (which ? p10 : p00) + k0;
        return (which ? p11 : p01) + (k0 - 480);
    };
    mgemm(aptr, WP_, KP1, 17, col0, acc);
    EPI_PRE
#pragma unroll
    for (int f=0; f<4; f++)
#pragma unroll
      for (int g=0; g<2; g++){
        int col = col0 + wn*32 + g*16 + (lane & 15);
        if (col >= HP) continue;
        float bc = (col < Hq) ? bW[col] : 0.f;
#pragma unroll
        for (int j=0; j<4; j++){
            int row = row0 + wm*64 + f*16 + ((lane>>4)<<2) + j;
            float v = (col < Hq) ? fmaxf(acc[f][g][j] + bc, 0.f) : 0.f;
            pv[(size_t)row*HP + col] = f2bf(v);
        }
      }
}

// ---------- pred GEMM2: pv @ Wo^T -> scores (f32, chunk) ----------
__global__ __launch_bounds__(256) void pred2_k(int cs,
    const ushort* __restrict__ pv, const ushort* __restrict__ WoP,
    const float* __restrict__ bWo, float* __restrict__ scores)
{
    const int row0 = blockIdx.y*128, col0 = blockIdx.x*64;
    const int tid = threadIdx.x;
    const ushort* p00 = pv + (size_t)(cs + row0 + (tid>>2))*HP;
    const ushort* p10 = pv + (size_t)(cs + row0 + (tid>>2) + 64)*HP;
    f32x4 acc[4][2];
    auto aptr = [&](int which,int k0)->const ushort*{
        return (which ? p10 : p00) + k0;
    };
    mgemm(aptr, WoP, KR, 15, col0, acc);
    EPI_PRE
#pragma unroll
    for (int f=0; f<4; f++)
#pragma unroll
      for (int g=0; g<2; g++){
        int col = col0 + wn*32 + g*16 + (lane & 15);
        if (col >= Vq) continue;
        float bc = bWo[col];
#pragma unroll
        for (int j=0; j<4; j++){
            int row = row0 + wm*64 + f*16 + ((lane>>4)<<2) + j;
            scores[(size_t)row*832 + col] = acc[f][g][j] + bc;
        }
      }
}

__global__ __launch_bounds__(256) void pred_reduce(int cs,
    const float* __restrict__ scores, const int* __restrict__ pred_wid,
    const int* __restrict__ root_wid, const int* __restrict__ valid,
    const int* __restrict__ direction, float* __restrict__ accv)
{
    __shared__ float rv[256]; __shared__ int ri[256]; __shared__ float rs[256];
    int r = blockIdx.x;
    int gr = cs + r;
    float mask; int tgt;
    if (gr < Bq){ mask = 1.f; tgt = root_wid[gr]; }
    else { int s = gr - Bq; mask = (float)(valid[s]*direction[s]); tgt = pred_wid[s]; }
    const float* sc = scores + (size_t)r*832;
    int tid = threadIdx.x;
    float bv = -INFINITY; int bi = 0;
    for (int j=tid;j<Vq;j+=256){ float v = sc[j]; if (v > bv){ bv=v; bi=j; } }
    rv[tid]=bv; ri[tid]=bi; __syncthreads();
    for (int off=128; off; off>>=1){
        if (tid < off){
            float v2 = rv[tid+off]; int i2 = ri[tid+off];
            if (v2 > rv[tid] || (v2 == rv[tid] && i2 < ri[tid])){ rv[tid]=v2; ri[tid]=i2; }
        }
        __syncthreads();
    }
    float gmax = rv[0]; int gidx = ri[0];
    float ls = 0.f;
    for (int j=tid;j<Vq;j+=256) ls += expf(sc[j]-gmax);
    rs[tid]=ls; __syncthreads();
    for (int off=128; off; off>>=1){ if (tid<off) rs[tid]+=rs[tid+off]; __syncthreads(); }
    if (tid==0){
        float lse = gmax + logf(rs[0]);
        float ce = lse - sc[tgt];
        atomicAdd(&accv[0], ce*mask);
        atomicAdd(&accv[1], (gidx==tgt ? 1.f : 0.f)*mask);
        atomicAdd(&accv[2], mask);
    }
}

// ---------- stop: cur_o gather (bf16) ----------
__global__ void curo_k(const int* __restrict__ o_nei_idx,
                       const int* __restrict__ root_o_nei,
                       const ushort* __restrict__ hbuf, ushort* __restrict__ curo)
{
    int r = blockIdx.x;
    int j0 = threadIdx.x * 4;
    if (j0 >= HP) return;
    int idx[Mq];
    if (r < TBq){
        int tt = r >> 9;
#pragma unroll
        for (int m=0;m<Mq;m++){
            int ix = o_nei_idx[(size_t)r*Mq + m];
            idx[m] = (ix <= tt*Bq) ? ix : 0;     // only slots written at steps < tt; row 0 is zero
        }
    } else {
#pragma unroll
        for (int m=0;m<Mq;m++) idx[m] = root_o_nei[(size_t)(r-TBq)*Mq + m];
    }
    float s0=0,s1=0,s2=0,s3=0;
#pragma unroll
    for (int m=0;m<Mq;m++){
        uint2 v = *(const uint2*)(hbuf + (size_t)idx[m]*HP + j0);
        s0 += bf2f((ushort)(v.x & 0xffff)); s1 += bf2f((ushort)(v.x >> 16));
        s2 += bf2f((ushort)(v.y & 0xffff)); s3 += bf2f((ushort)(v.y >> 16));
    }
    uint2 o;
    o.x = (unsigned)f2bf(s0) | ((unsigned)f2bf(s1) << 16);
    o.y = (unsigned)f2bf(s2) | ((unsigned)f2bf(s3) << 16);
    *(uint2*)(curo + (size_t)r*HP + j0) = o;
}

// ---------- stop GEMM: [xe|curo|tv] @ U^T, relu, fused Us-dot -> ss[row] ----------
__global__ __launch_bounds__(256) void stop_k(
    const int* __restrict__ x_wid, const int* __restrict__ root_wid,
    const ushort* __restrict__ embb, const ushort* __restrict__ curo,
    const ushort* __restrict__ treeb, const ushort* __restrict__ UP_,
    const float* __restrict__ bU, const float* __restrict__ Usf,
    float* __restrict__ ss)
{
    const int row0 = blockIdx.y*128, col0 = blockIdx.x*64;
    const int tid = threadIdx.x;
    int gr0 = row0 + (tid>>2), gr1 = gr0 + 64;
    int wid0 = (gr0 < TBq) ? x_wid[gr0] : root_wid[gr0 - TBq];
    int wid1 = (gr1 < TBq) ? x_wid[gr1] : root_wid[gr1 - TBq];
    const ushort* p00 = embb + (size_t)wid0*HP;
    const ushort* p10 = embb + (size_t)wid1*HP;
    const ushort* p01 = curo + (size_t)gr0*HP;
    const ushort* p11 = curo + (size_t)gr1*HP;
    int b0 = (gr0 < TBq) ? (gr0 & (Bq-1)) : (gr0 - TBq);
    int b1 = (gr1 < TBq) ? (gr1 & (Bq-1)) : (gr1 - TBq);
    const ushort* p02 = treeb + (size_t)b0*64;
    const ushort* p12 = treeb + (size_t)b1*64;
    f32x4 acc[4][2];
    auto aptr = [&](int which,int k0)->const ushort*{
        if (k0 < 480)  return (which ? p10 : p00) + k0;
        if (k0 < 960)  return (which ? p11 : p01) + (k0 - 480);
        return (which ? p12 : p02) + (k0 - 960);
    };
    mgemm(aptr, UP_, KS, 32, col0, acc);
    EPI_PRE
#pragma unroll
    for (int f=0; f<4; f++){
#pragma unroll
        for (int j=0; j<4; j++){
            float p = 0.f;
#pragma unroll
            for (int g=0; g<2; g++){
                int col = col0 + wn*32 + g*16 + (lane & 15);
                if (col < Hq)
                    p += fmaxf(acc[f][g][j] + bU[col], 0.f) * Usf[col];
            }
            p += __shfl_xor(p, 1); p += __shfl_xor(p, 2);
            p += __shfl_xor(p, 4); p += __shfl_xor(p, 8);
            if ((lane & 15) == 0){
                int row = row0 + wm*64 + f*16 + ((lane>>4)<<2) + j;
                atomicAdd(&ss[row], p);
            }
        }
    }
}

__global__ void stop_final(const float* __restrict__ ss, const float* __restrict__ bUs,
                           const int* __restrict__ valid, const int* __restrict__ direction,
                           float* __restrict__ accv)
{
    int gr = blockIdx.x*256 + threadIdx.x;       // 130*256 = 33280 exact
    float s = ss[gr] + bUs[0];
    float stgt, sm;
    if (gr < TBq){ stgt = (float)direction[gr]; sm = (float)valid[gr]; }
    else { stgt = 0.f; sm = 1.f; }
    float bce = (fmaxf(s,0.f) - s*stgt + log1pf(expf(-fabsf(s)))) * sm;
    float hit = (((s >= 0.f) ? 1.f : 0.f) == stgt ? 1.f : 0.f) * sm;
    // wave reduce then one atomic per wave
    for (int off=32; off; off>>=1){
        bce += __shfl_down(bce, off);
        hit += __shfl_down(hit, off);
        sm  += __shfl_down(sm,  off);
    }
    if ((threadIdx.x & 63) == 0){
        atomicAdd(&accv[3], bce);
        atomicAdd(&accv[4], hit);
        atomicAdd(&accv[5], sm);
    }
}

__global__ void finalize_k(const float* __restrict__ accv, float* __restrict__ out){
    if (threadIdx.x==0){
        out[0] = accv[0] / (float)Bq;
        out[1] = accv[3] / (float)Bq;
        out[2] = accv[1] / accv[2];
        out[3] = accv[4] / accv[5];
    }
}

extern "C" void kernel_launch(void* const* d_in, const int* in_sizes, int n_in,
                              void* d_out, int out_size, void* d_ws, size_t ws_size,
                              hipStream_t stream) {
    (void)in_sizes; (void)n_in; (void)out_size; (void)ws_size;
    const float* tree_vecs = (const float*)d_in[0];
    const int*   x_wid     = (const int*)d_in[1];
    const int*   pred_wid  = (const int*)d_in[2];
    const int*   root_wid  = (const int*)d_in[3];
    const int*   h_nei_idx = (const int*)d_in[4];
    const int*   o_nei_idx = (const int*)d_in[5];
    const int*   root_o_nei= (const int*)d_in[6];
    const int*   valid     = (const int*)d_in[7];
    const int*   direction = (const int*)d_in[8];
    const float* emb       = (const float*)d_in[9];
    const float* Wz        = (const float*)d_in[10];
    const float* bz        = (const float*)d_in[11];
    const float* Wr        = (const float*)d_in[12];
    const float* br        = (const float*)d_in[13];
    const float* Ur        = (const float*)d_in[14];
    const float* Wh        = (const float*)d_in[15];
    const float* bh        = (const float*)d_in[16];
    const float* Wm        = (const float*)d_in[17];
    const float* bW        = (const float*)d_in[18];
    const float* U         = (const float*)d_in[19];
    const float* bU        = (const float*)d_in[20];
    const float* Wo        = (const float*)d_in[21];
    const float* bWo       = (const float*)d_in[22];
    const float* Us        = (const float*)d_in[23];
    const float* bUs       = (const float*)d_in[24];

    char* w = (char*)d_ws; size_t off = 0;
    auto alloc = [&](size_t bytes)->void*{ void* p = w + off; off += (bytes + 255) & ~(size_t)255; return p; };

    ushort* hbuf  = (ushort*)alloc((size_t)Sq*HP*2);
    ushort* embb  = (ushort*)alloc((size_t)Vq*HP*2);
    ushort* treeb = (ushort*)alloc((size_t)Bq*64*2);
    ushort* WzP   = (ushort*)alloc((size_t)512*KZ*2);
    ushort* WrP   = (ushort*)alloc((size_t)512*KR*2);
    ushort* UrP   = (ushort*)alloc((size_t)512*KR*2);
    ushort* WhP   = (ushort*)alloc((size_t)512*KZ*2);
    ushort* WP_   = (ushort*)alloc((size_t)512*KP1*2);
    ushort* WoP   = (ushort*)alloc((size_t)832*KR*2);
    ushort* UP_   = (ushort*)alloc((size_t)512*KS*2);
    ushort* sumh  = (ushort*)alloc((size_t)Bq*HP*2);
    ushort* xh2   = (ushort*)alloc((size_t)Bq*HP*2);
    float*  pre_z = (float*)alloc((size_t)Bq*F32S*4);
    float*  pre_r = (float*)alloc((size_t)Bq*F32S*4);
    float*  urb   = (float*)alloc((size_t)Bq*Mq*F32S*4);
    ushort* pv    = (ushort*)alloc((size_t)(TBq+Bq)*HP*2);   // reused as curo in stop phase
    float*  scores= (float*)alloc((size_t)CH*832*4);
    float*  ss    = (float*)alloc((size_t)(TBq+Bq)*4 + 64);
    float*  accv  = ss + (TBq+Bq);

    hipMemsetAsync(hbuf, 0, (size_t)Sq*HP*2, stream);
    hipMemsetAsync(ss, 0, (size_t)(TBq+Bq)*4 + 64, stream);

    // converters
    convW_k<<<Vq,  256, 0, stream>>>(emb, embb, Vq, Hq, HP, Hq, 0, 0);
    convW_k<<<Bq,  256, 0, stream>>>(tree_vecs, treeb, Bq, Lq, 64, Lq, 0, 0);
    convW_k<<<512, 256, 0, stream>>>(Wz, WzP, Hq, 2*Hq, KZ, Hq, Hq, 0);
    convW_k<<<512, 256, 0, stream>>>(Wr, WrP, Hq, Hq, KR, Hq, 0, 0);
    convW_k<<<512, 256, 0, stream>>>(Ur, UrP, Hq, Hq, KR, Hq, 0, 0);
    convW_k<<<512, 256, 0, stream>>>(Wh, WhP, Hq, 2*Hq, KZ, Hq, Hq, 0);
    convW_k<<<512, 256, 0, stream>>>(Wm, WP_, Hq, Hq+Lq, KP1, Hq, Lq, 0);
    convW_k<<<832, 256, 0, stream>>>(Wo, WoP, Vq, Hq, KR, Hq, 0, 0);
    convW_k<<<512, 256, 0, stream>>>(U,  UP_, Hq, Lq+2*Hq, KS, Hq, Hq, Lq);

    // sequential scan
    for (int t=0; t<Tq; t++){
        prep_k <<<Bq, 128, 0, stream>>>(t, h_nei_idx, hbuf, sumh);
        zru_k  <<<dim3(8, 32, 3), 256, 0, stream>>>(t, x_wid, h_nei_idx, embb, sumh, hbuf,
                                                    WzP, WrP, UrP, pre_z, pre_r, urb);
        gated_k<<<Bq, 128, 0, stream>>>(t, h_nei_idx, hbuf, pre_r, br, urb, xh2);
        wh_k   <<<dim3(8, 4), 256, 0, stream>>>(t, x_wid, embb, xh2, WhP, pre_z, sumh,
                                                bz, bh, valid, hbuf);
    }

    // pred phase
    pred1_k<<<dim3(8, 260), 256, 0, stream>>>(hbuf, treeb, WP_, bW, pv);
    for (int c=0; c<NCH; c++){
        int cs = c*CH;
        pred2_k<<<dim3(13, CH/128), 256, 0, stream>>>(cs, pv, WoP, bWo, scores);
        pred_reduce<<<CH, 256, 0, stream>>>(cs, scores, pred_wid, root_wid, valid, direction, accv);
    }

    // stop phase (curo reuses pv buffer)
    ushort* curo = pv;
    curo_k<<<TBq+Bq, 128, 0, stream>>>(o_nei_idx, root_o_nei, hbuf, curo);
    stop_k<<<dim3(8, 260), 256, 0, stream>>>(x_wid, root_wid, embb, curo, treeb, UP_, bU, Us, ss);
    stop_final<<<130, 256, 0, stream>>>(ss, bUs, valid, direction, accv);

    finalize_k<<<1, 64, 0, stream>>>(accv, (float*)d_out);
}